// Round 12
// baseline (1250.257 us; speedup 1.0000x reference)
//
#include <hip/hip_runtime.h>
#include <hip/hip_bf16.h>

#define N_NODES 163840
#define N_EDGES 2621440
#define NB      4096

typedef __hip_bfloat16 bf16;
typedef __attribute__((ext_vector_type(8))) short short8;
typedef __attribute__((ext_vector_type(4))) float floatx4;

__device__ inline float tofloat(float v) { return v; }
__device__ inline float tofloat(bf16 v) { return __bfloat162float(v); }
__device__ inline void storev(float* p, float v) { *p = v; }
__device__ inline void storev(bf16* p, float v) { *p = __float2bfloat16(v); }
__device__ inline float s2f(short s) {
  union { unsigned u; float f; } cv;
  cv.u = ((unsigned)(unsigned short)s) << 16;
  return cv.f;
}
__device__ inline short f2s(float f) {
  bf16 b = __float2bfloat16(f);
  return *(short*)&b;
}

// ======================= graph preprocessing =======================

__global__ __launch_bounds__(256) void count_kernel(const int* __restrict__ ei,
                                                    int* __restrict__ indeg) {
  int e = blockIdx.x * 256 + threadIdx.x;
  if (e < N_EDGES) atomicAdd(&indeg[ei[N_EDGES + e]], 1);
}

// block-scan over indeg; also emits dinv = rsqrt(indeg+1)
__global__ __launch_bounds__(256) void scan1_kernel(const int* __restrict__ indeg,
                                                    int* __restrict__ rowstart,
                                                    int* __restrict__ bsums,
                                                    float* __restrict__ dinv) {
  __shared__ int s[256];
  int tid = threadIdx.x;
  int i = blockIdx.x * 256 + tid;
  int v = indeg[i];
  dinv[i] = rsqrtf((float)v + 1.0f);
  s[tid] = v;
  __syncthreads();
  for (int off = 1; off < 256; off <<= 1) {
    int x = (tid >= off) ? s[tid - off] : 0;
    __syncthreads();
    s[tid] += x;
    __syncthreads();
  }
  rowstart[i] = s[tid] - v;
  if (tid == 255) bsums[blockIdx.x] = s[255];
}

// parallel scan over the 640 block sums (single 640-thread block)
__global__ __launch_bounds__(640) void scan2_kernel(const int* __restrict__ bsums,
                                                    int* __restrict__ boffs,
                                                    int* __restrict__ rowstart) {
  __shared__ int s[640];
  int tid = threadIdx.x;
  int v = bsums[tid];
  s[tid] = v;
  __syncthreads();
  for (int off = 1; off < 640; off <<= 1) {
    int x = (tid >= off) ? s[tid - off] : 0;
    __syncthreads();
    s[tid] += x;
    __syncthreads();
  }
  boffs[tid] = s[tid] - v;  // exclusive
  if (tid == 639) rowstart[N_NODES] = s[639];
}

__global__ __launch_bounds__(256) void scan3_kernel(int* __restrict__ rowstart,
                                                    int* __restrict__ cursor,
                                                    const int* __restrict__ boffs) {
  int i = blockIdx.x * 256 + threadIdx.x;
  int v = rowstart[i] + boffs[blockIdx.x];
  rowstart[i] = v;
  cursor[i] = v;
}

// Bucketed scatter: pass p = blockIdx.y commits only dst in [p*N/4,(p+1)*N/4).
__global__ __launch_bounds__(256) void scatter_kernel(const int* __restrict__ ei,
                                                      int* __restrict__ cursor,
                                                      int* __restrict__ csr_src) {
  int e = blockIdx.x * 256 + threadIdx.x;
  int lo = blockIdx.y * (N_NODES / 4);
  int hi = lo + (N_NODES / 4);
  if (e < N_EDGES) {
    int d = ei[N_EDGES + e];
    if (d >= lo && d < hi) {
      int pos = atomicAdd(&cursor[d], 1);
      csr_src[pos] = ei[e];
    }
  }
}

// xb[n, 0:78] = x[n,:] * dinv[n]; cols 78..79 = 0  (padded [N,80] layout)
__global__ __launch_bounds__(256) void cast_scale_kernel(const float* __restrict__ x,
                                                         const float* __restrict__ dinv,
                                                         bf16* __restrict__ xb) {
  int i = blockIdx.x * 256 + threadIdx.x;
  if (i < N_NODES * 80) {
    int n = i / 80, f = i - n * 80;
    float v = (f < 78) ? x[n * 78 + f] * dinv[n] : 0.f;
    xb[i] = __float2bfloat16(v);
  }
}

// ============ fused GCN layer: gather-aggregate (F=80) + MFMA transform ============
// hs pre-scaled (hs[n] = h[n]*dinv[n], cols>=Nc_prev zero).
// Phase 1 (per wave): 16 nodes, agg row = dn*(sum_src hs[src] + hs[n]) -> LDS.
// Phase 2 (same wave, own rows only -> no barrier): A[16x80] @ Bt -> relu(.+b)*dinv.
template <int NT>
__global__ __launch_bounds__(256) void gcn_fused_kernel(
    const bf16* __restrict__ hs, const float* __restrict__ dinv,
    const int* __restrict__ rowstart, const int* __restrict__ csr,
    const bf16* __restrict__ Bt, const float* __restrict__ bias,
    bf16* __restrict__ hout, int Nc, int ldc) {
  __shared__ __align__(16) bf16 a_s[64 * 88 + 8];  // rows padded 80->88 (2-way ok)
  int tid = threadIdx.x;
  int w = tid >> 6, lane = tid & 63;
  int quad = lane >> 4, l16 = lane & 15;
  int grp = lane / 10, sub = lane - grp * 10;  // 6 groups x 10 chunks
  bool active = grp < 6;
  int nbase = blockIdx.x * 64 + w * 16;

  // ---- phase 1: aggregate 16 nodes into LDS rows w*16 .. w*16+15 ----
  for (int t = 0; t < 16; t++) {
    int node = nbase + t;
    int st = rowstart[node], en = rowstart[node + 1];
    int cnt = en - st + 1;  // edges + self
    float acc[8];
#pragma unroll
    for (int j = 0; j < 8; j++) acc[j] = 0.f;
    for (int e = 0; e < cnt; e += 6) {
      int ri = e + grp;
      bool valid = active && (ri < cnt);
      int cidx = st + ri;
      cidx = (cidx < en) ? cidx : 0;
      int row = (ri < cnt - 1) ? csr[cidx] : node;
      const short* rp = (const short*)hs + (size_t)row * 80 + sub * 8;
      short8 d = *(const short8*)rp;
      float m = valid ? 1.f : 0.f;
#pragma unroll
      for (int j = 0; j < 8; j++) acc[j] += m * s2f(d[j]);
    }
    float dn = dinv[node];
    short8 pk;
#pragma unroll
    for (int j = 0; j < 8; j++) {
      float v = acc[j];
      float s = 0.f;
#pragma unroll
      for (int g = 0; g < 6; g++) s += __shfl(v, sub + 10 * g);
      pk[j] = f2s(s * dn);
    }
    if (grp == 0)
      *(short8*)&a_s[(w * 16 + t) * 88 + sub * 8] = pk;
  }
  // no __syncthreads: each wave reads only rows it wrote

  // ---- phase 2: MFMA (K=80, Ksteps=3 with zero-padded Bt kpad=96) ----
  floatx4 acc2[NT];
#pragma unroll
  for (int t = 0; t < NT; t++) acc2[t] = (floatx4){0.f, 0.f, 0.f, 0.f};
  const short* Ap = (const short*)&a_s[(w * 16 + l16) * 88 + quad * 8];
  const short* Bp = (const short*)Bt + (size_t)l16 * 96 + quad * 8;
#pragma unroll
  for (int s = 0; s < 3; s++) {
    short8 a = *(const short8*)(Ap + s * 32);
#pragma unroll
    for (int t = 0; t < NT; t++) {
      short8 b = *(const short8*)(Bp + (size_t)t * 16 * 96 + s * 32);
      acc2[t] = __builtin_amdgcn_mfma_f32_16x16x32_bf16(a, b, acc2[t], 0, 0, 0);
    }
  }
#pragma unroll
  for (int t = 0; t < NT; t++) {
    int c = t * 16 + l16;
    bool valid = c < Nc;
    float bb = valid ? bias[c] : 0.f;
#pragma unroll
    for (int r = 0; r < 4; r++) {
      int row = nbase + quad * 4 + r;
      float v = valid ? acc2[t][r] + bb : 0.f;
      v = fmaxf(v, 0.f) * dinv[row];
      storev(&hout[(size_t)row * ldc + c], v);
    }
  }
}

// F=192 gather (384 B rows = 3 aligned lines), writes 160-wide.
__global__ __launch_bounds__(256) void agg192_kernel(const bf16* __restrict__ hs,
                                                     const float* __restrict__ dinv,
                                                     const int* __restrict__ rowstart,
                                                     const int* __restrict__ csr,
                                                     bf16* __restrict__ out) {
  int node = blockIdx.x * 4 + (threadIdx.x >> 6);
  int lane = threadIdx.x & 63;
  int grp = lane >> 3;
  int sub = lane & 7;
  int st = rowstart[node], en = rowstart[node + 1];
  int cnt = en - st + 1;
  float dn = dinv[node];
  float acc[3][8];
#pragma unroll
  for (int k = 0; k < 3; k++)
#pragma unroll
    for (int j = 0; j < 8; j++) acc[k][j] = 0.f;
  for (int e = 0; e < cnt; e += 8) {
    int ri = e + grp;
    bool valid = ri < cnt;
    int cidx = st + ri;
    cidx = (cidx < en) ? cidx : 0;
    int row = (ri < cnt - 1) ? csr[cidx] : node;
    const short* rp = (const short*)hs + (size_t)row * 192 + sub * 8;
    float m = valid ? 1.f : 0.f;
#pragma unroll
    for (int k = 0; k < 3; k++) {
      short8 d = *(const short8*)(rp + k * 64);
#pragma unroll
      for (int j = 0; j < 8; j++) acc[k][j] += m * s2f(d[j]);
    }
  }
#pragma unroll
  for (int k = 0; k < 3; k++) {
    short8 pk;
#pragma unroll
    for (int j = 0; j < 8; j++) {
      float v = acc[k][j];
      v += __shfl_xor(v, 8);
      v += __shfl_xor(v, 16);
      v += __shfl_xor(v, 32);
      pk[j] = f2s(v * dn);
    }
    if (grp == 0 && (k < 2 || sub < 4))
      *(short8*)((short*)out + (size_t)node * 160 + k * 64 + sub * 8) = pk;
  }
}

// ======================= MFMA GEMM (direct-register, no LDS) =======================
template <int NT, typename TC>
__global__ __launch_bounds__(256) void gemm_mfma_kernel(
    const bf16* __restrict__ A, const bf16* __restrict__ Bt,
    const float* __restrict__ bias, const float* __restrict__ rowScale,
    TC* __restrict__ C, int M, int Nc, int ncstore, int Ksteps, int lda,
    int kpad, int ldc, int coff, int doRelu) {
  int tid = threadIdx.x;
  int w = tid >> 6, lane = tid & 63;
  int quad = lane >> 4, l16 = lane & 15;
  int r0 = blockIdx.x * 64 + w * 16;
  int c0 = blockIdx.y * (NT * 16);
  floatx4 acc[NT];
#pragma unroll
  for (int t = 0; t < NT; t++) acc[t] = (floatx4){0.f, 0.f, 0.f, 0.f};
  const short* Ap = (const short*)A + (size_t)(r0 + l16) * lda + quad * 8;
  const short* Bp = (const short*)Bt + (size_t)(c0 + l16) * kpad + quad * 8;
  for (int s = 0; s < Ksteps; s++) {
    short8 a = *(const short8*)(Ap + s * 32);
#pragma unroll
    for (int t = 0; t < NT; t++) {
      short8 b = *(const short8*)(Bp + (size_t)t * 16 * kpad + s * 32);
      acc[t] = __builtin_amdgcn_mfma_f32_16x16x32_bf16(a, b, acc[t], 0, 0, 0);
    }
  }
#pragma unroll
  for (int t = 0; t < NT; t++) {
    int c = c0 + t * 16 + l16;
    if (c >= ncstore) continue;
    bool valid = c < Nc;
    float bb = (bias && valid) ? bias[c] : 0.f;
#pragma unroll
    for (int r = 0; r < 4; r++) {
      int row = r0 + quad * 4 + r;
      float v = valid ? acc[t][r] + bb : 0.f;
      if (doRelu) v = fmaxf(v, 0.f);
      if (rowScale) v *= rowScale[row];
      storev(&C[(size_t)row * ldc + coff + c], v);
    }
  }
}

// ================== merged weight prep + indeg zero (one launch) ==================
__device__ inline void wtrans_one(const float* __restrict__ W, bf16* __restrict__ Bt,
                                  int K, int N, int Kpad, int idx) {
  int n = idx / Kpad, k = idx - n * Kpad;
  float v = (k < K && n < N) ? W[(size_t)k * N + n] : 0.f;
  Bt[idx] = __float2bfloat16(v);
}
template <int CI, int NCO>
__device__ inline void wprep_one(const float* __restrict__ kw, bf16* __restrict__ Wr,
                                 int idx) {
  int co = idx % NCO, k = idx / NCO;
  int dl = k / CI, ci = k % CI;
  Wr[idx] = __float2bfloat16(kw[(co * CI + ci) * 8 + dl]);
}
__global__ __launch_bounds__(256) void wprep_all_kernel(
    const float* k2, const float* k3, const float* W1, const float* W2,
    const float* W3, const float* Wg1, const float* Wg2, const float* Wxt,
    const float* Wf1, const float* Wf2, bf16* Wr2, bf16* Wr3, bf16* Btw1,
    bf16* Btw2, bf16* BtW3, bf16* Btg1, bf16* Btg2, bf16* Btxt, bf16* Btf1,
    bf16* Btf2, int* indeg) {
  int idx = blockIdx.x * 256 + threadIdx.x;
  if (idx < N_NODES) { indeg[idx] = 0; return; }
  idx -= N_NODES;
  if (idx < 16384) { wprep_one<32, 64>(k2, Wr2, idx); return; }
  idx -= 16384;
  if (idx < 65536) { wprep_one<64, 128>(k3, Wr3, idx); return; }
  idx -= 65536;
  if (idx < 7680) { wtrans_one(W1, Btw1, 78, 78, 96, idx); return; }
  idx -= 7680;
  if (idx < 15360) { wtrans_one(W2, Btw2, 78, 156, 96, idx); return; }
  idx -= 15360;
  if (idx < 51200) { wtrans_one(W3, BtW3, 156, 312, 160, idx); return; }
  idx -= 51200;
  if (idx < 327680) { wtrans_one(Wg1, Btg1, 312, 1024, 320, idx); return; }
  idx -= 327680;
  if (idx < 131072) { wtrans_one(Wg2, Btg2, 1024, 128, 1024, idx); return; }
  idx -= 131072;
  if (idx < 376832) {  // Wxt permuted transpose
    int o = idx / 2944, k = idx - o * 2944;
    int l = k >> 7, co = k & 127;
    Btxt[idx] = __float2bfloat16(Wxt[((size_t)(co * 23 + l)) * 128 + o]);
    return;
  }
  idx -= 376832;
  if (idx < 262144) { wtrans_one(Wf1, Btf1, 256, 1024, 256, idx); return; }
  idx -= 262144;
  if (idx < 131072) { wtrans_one(Wf2, Btf2, 1024, 128, 1024, idx); return; }
}
#define WPREP_TOTAL (N_NODES + 16384 + 65536 + 7680 + 15360 + 51200 + 327680 + 131072 + 376832 + 262144 + 131072)

// ======= fused layer-3 GCN transform + bias + relu + segment-max (MFMA) =============
__global__ __launch_bounds__(256) void gcn3_segmax_mfma_kernel(
    const bf16* __restrict__ agg2, const bf16* __restrict__ BtW3,
    const float* __restrict__ b3, bf16* __restrict__ g) {
  __shared__ __align__(16) bf16 a_lds[160 * 168];
  int tid = threadIdx.x;
  int w = tid >> 6, lane = tid & 63;
  int quad = lane >> 4, l16 = lane & 15;
  int g0 = blockIdx.x * 4;

  short8 bfrag[5][5];
  const short* Bp = (const short*)BtW3 + (size_t)(w * 80 + l16) * 160 + quad * 8;
#pragma unroll
  for (int nt = 0; nt < 5; nt++)
#pragma unroll
    for (int ks = 0; ks < 5; ks++)
      bfrag[nt][ks] = *(const short8*)(Bp + (size_t)nt * 16 * 160 + ks * 32);

  const bf16* src = agg2 + (size_t)g0 * 40 * 160;
  for (int i = tid; i < 160 * 160 / 8; i += 256) {
    int flat = i * 8;
    int row = flat / 160, k = flat - row * 160;
    *(short8*)&a_lds[row * 168 + k] = *(const short8*)&src[flat];
  }
  __syncthreads();

  float gmax[5][4];
#pragma unroll
  for (int nt = 0; nt < 5; nt++)
#pragma unroll
    for (int gi = 0; gi < 4; gi++) gmax[nt][gi] = -3.0e38f;

#pragma unroll
  for (int mt = 0; mt < 10; mt++) {
    floatx4 acc[5];
#pragma unroll
    for (int nt = 0; nt < 5; nt++) acc[nt] = (floatx4){0.f, 0.f, 0.f, 0.f};
#pragma unroll
    for (int ks = 0; ks < 5; ks++) {
      short8 a = *(const short8*)&a_lds[(16 * mt + l16) * 168 + ks * 32 + quad * 8];
#pragma unroll
      for (int nt = 0; nt < 5; nt++)
        acc[nt] = __builtin_amdgcn_mfma_f32_16x16x32_bf16(a, bfrag[nt][ks], acc[nt], 0, 0, 0);
    }
    int gl = (16 * mt + quad * 4) / 40;
#pragma unroll
    for (int nt = 0; nt < 5; nt++) {
      float m4 = fmaxf(fmaxf(acc[nt][0], acc[nt][1]), fmaxf(acc[nt][2], acc[nt][3]));
#pragma unroll
      for (int gi = 0; gi < 4; gi++)
        if (gl == gi) gmax[nt][gi] = fmaxf(gmax[nt][gi], m4);
    }
  }

#pragma unroll
  for (int nt = 0; nt < 5; nt++) {
#pragma unroll
    for (int gi = 0; gi < 4; gi++) {
      float v = gmax[nt][gi];
      v = fmaxf(v, __shfl_xor(v, 16));
      v = fmaxf(v, __shfl_xor(v, 32));
      gmax[nt][gi] = v;
    }
    int c = w * 80 + nt * 16 + l16;
    float bb = (c < 312) ? b3[c] : 0.f;
    float val = fmaxf(gmax[nt][quad] + bb, 0.f);
    g[(size_t)(g0 + quad) * 320 + c] = __float2bfloat16(val);
  }
}

// ========== fused conv1+conv2: xo [B,735] -> c2 [B,78,64] (MFMA conv2) =============
__global__ __launch_bounds__(256) void conv12_kernel(const float* __restrict__ xo,
                                                     const float* __restrict__ k1,
                                                     const float* __restrict__ kb1,
                                                     const bf16* __restrict__ Wr2,
                                                     const float* __restrict__ kb2,
                                                     bf16* __restrict__ outp) {
  constexpr int LPAD = 248, MT = 15, LOUT = 78, G = 2, NCO = 64, CIP = 40;
  __shared__ __align__(16) bf16 lds_in[G * LPAD * CIP];
  __shared__ bf16 stg[4][MT * 16][16];
  __shared__ float xo_s[G][736];
  __shared__ float k1w[256];
  __shared__ float kb1s[32];
  int tid = threadIdx.x;
  int w = tid >> 6, lane = tid & 63;
  int quad = lane >> 4, l16 = lane & 15;
  int bg = blockIdx.x;
  int co0 = w * 16;

  short8 bfrag[8];
#pragma unroll
  for (int s = 0; s < 8; s++) {
#pragma unroll
    for (int j = 0; j < 8; j++) {
      int k = s * 32 + quad * 8 + j;
      bfrag[s][j] = ((const short*)Wr2)[k * NCO + co0 + l16];
    }
  }

  for (int i = tid; i < G * 735; i += 256)
    xo_s[i / 735][i % 735] = xo[(size_t)(bg * G + i / 735) * 735 + i % 735];
  k1w[tid] = k1[tid];
  if (tid < 32) kb1s[tid] = kb1[tid];
  __syncthreads();

  for (int idx = tid; idx < G * 242 * 32; idx += 256) {
    int g = idx / (242 * 32);
    int rem = idx - g * (242 * 32);
    int l = rem >> 5, co = rem & 31;
    int base = l * 3;
    float bs = kb1s[co];
    float a0 = bs, a1 = bs, a2 = bs;
#pragma unroll
    for (int k = 0; k < 8; k++) {
      float wv = k1w[co * 8 + k];
      a0 += wv * xo_s[g][base + k];
      a1 += wv * xo_s[g][base + 1 + k];
      a2 += wv * xo_s[g][base + 2 + k];
    }
    lds_in[(g * LPAD + l) * CIP + co] =
        __float2bfloat16(fmaxf(0.f, fmaxf(a0, fmaxf(a1, a2))));
  }
  for (int i = tid; i < G * 6 * 32; i += 256) {
    int g = i / (6 * 32);
    int rem = i - g * (6 * 32);
    int r = rem >> 5, c = rem & 31;
    lds_in[(g * LPAD + 242 + r) * CIP + c] = __float2bfloat16(0.f);
  }
  __syncthreads();

  for (int g = 0; g < G; g++) {
    const bf16* base = &lds_in[g * LPAD * CIP];
#pragma unroll
    for (int mt = 0; mt < MT; mt++) {
      floatx4 acc = {0.f, 0.f, 0.f, 0.f};
      int m = mt * 16 + l16;
#pragma unroll
      for (int s = 0; s < 8; s++) {
        int kg0 = s * 32 + quad * 8;
        int dl = kg0 >> 5;
        int ci0 = kg0 & 31;
        short8 a = *(const short8*)&base[(m + dl) * CIP + ci0];
        acc = __builtin_amdgcn_mfma_f32_16x16x32_bf16(a, bfrag[s], acc, 0, 0, 0);
      }
#pragma unroll
      for (int r = 0; r < 4; r++)
        stg[w][mt * 16 + quad * 4 + r][l16] = __float2bfloat16(acc[r]);
    }
    __syncthreads();
    float bias = kb2[co0 + l16];
    for (int it = lane; it < LOUT * 16; it += 64) {
      int l = it >> 4;
      float v0 = __bfloat162float(stg[w][3 * l][l16]);
      float v1 = __bfloat162float(stg[w][3 * l + 1][l16]);
      float v2 = __bfloat162float(stg[w][3 * l + 2][l16]);
      float v = fmaxf(fmaxf(v0, v1), v2) + bias;
      outp[((size_t)(bg * G + g) * LOUT + l) * NCO + co0 + l16] =
          __float2bfloat16(fmaxf(v, 0.f));
    }
    __syncthreads();
  }
}

// ======================= MFMA implicit-GEMM conv3 + bias + relu + pool3 =============
template <int CI, int LIN, int LPAD, int MT, int LOUT, int G, int NCO>
__global__ __launch_bounds__(256) void convmfma_kernel(const bf16* __restrict__ in,
                                                       const bf16* __restrict__ Wr,
                                                       const float* __restrict__ kb,
                                                       bf16* __restrict__ outp) {
  constexpr int KSTEPS = 8 * CI / 32;
  constexpr int CIP = CI + 8;
  __shared__ __align__(16) bf16 lds_in[G * LPAD * CIP];
  __shared__ bf16 stg[4][MT * 16][16];
  int tid = threadIdx.x;
  int w = tid >> 6, lane = tid & 63;
  int quad = lane >> 4, l16 = lane & 15;
  int bg = blockIdx.x;
  int co0 = blockIdx.y * 64 + w * 16;

  short8 bfrag[KSTEPS];
#pragma unroll
  for (int s = 0; s < KSTEPS; s++) {
#pragma unroll
    for (int j = 0; j < 8; j++) {
      int k = s * 32 + quad * 8 + j;
      bfrag[s][j] = ((const short*)Wr)[k * NCO + co0 + l16];
    }
  }

  const bf16* gin = in + (size_t)bg * G * LIN * CI;
  constexpr int NELEM = G * LIN * CI;
  for (int i = tid; i < NELEM / 8; i += 256) {
    int flat = i * 8;
    int g = flat / (LIN * CI);
    int rem = flat - g * (LIN * CI);
    int row = rem / CI, ci = rem - row * CI;
    *(short8*)&lds_in[(g * LPAD + row) * CIP + ci] = *(const short8*)&gin[flat];
  }
  constexpr int PADE = G * (LPAD - LIN) * CIP;
  for (int i = tid; i < PADE / 8; i += 256) {
    int flat = i * 8;
    int g = flat / ((LPAD - LIN) * CIP);
    int rem = flat - g * ((LPAD - LIN) * CIP);
    short8 z = {0, 0, 0, 0, 0, 0, 0, 0};
    *(short8*)&lds_in[(g * LPAD + LIN) * CIP + rem] = z;
  }
  __syncthreads();

  for (int g = 0; g < G; g++) {
    const bf16* base = &lds_in[g * LPAD * CIP];
#pragma unroll
    for (int mt = 0; mt < MT; mt++) {
      floatx4 acc = {0.f, 0.f, 0.f, 0.f};
      int m = mt * 16 + l16;
#pragma unroll
      for (int s = 0; s < KSTEPS; s++) {
        int kg0 = s * 32 + quad * 8;
        int dl = kg0 / CI;
        int ci0 = kg0 % CI;
        short8 a = *(const short8*)&base[(m + dl) * CIP + ci0];
        acc = __builtin_amdgcn_mfma_f32_16x16x32_bf16(a, bfrag[s], acc, 0, 0, 0);
      }
#pragma unroll
      for (int r = 0; r < 4; r++)
        stg[w][mt * 16 + quad * 4 + r][l16] = __float2bfloat16(acc[r]);
    }
    __syncthreads();
    float bias = kb[co0 + l16];
    for (int it = lane; it < LOUT * 16; it += 64) {
      int l = it >> 4;
      float v0 = __bfloat162float(stg[w][3 * l][l16]);
      float v1 = __bfloat162float(stg[w][3 * l + 1][l16]);
      float v2 = __bfloat162float(stg[w][3 * l + 2][l16]);
      float v = fmaxf(fmaxf(v0, v1), v2) + bias;
      outp[((size_t)(bg * G + g) * LOUT + l) * NCO + co0 + l16] =
          __float2bfloat16(fmaxf(v, 0.f));
    }
    __syncthreads();
  }
}

// ======================= final head =======================
__global__ __launch_bounds__(256) void final_kernel(const float* __restrict__ f2,
                                                    const float* __restrict__ Wo,
                                                    const float* __restrict__ bo,
                                                    float* __restrict__ out) {
  int wid = (blockIdx.x * blockDim.x + threadIdx.x) >> 6;
  int lane = threadIdx.x & 63;
  if (wid >= NB) return;
  float s = f2[wid * 128 + lane] * Wo[lane] + f2[wid * 128 + 64 + lane] * Wo[64 + lane];
  for (int o = 32; o > 0; o >>= 1) s += __shfl_down(s, o);
  if (lane == 0) out[wid] = s + bo[0];
}

// ======================= launch =======================
extern "C" void kernel_launch(void* const* d_in, const int* in_sizes, int n_in,
                              void* d_out, int out_size, void* d_ws, size_t ws_size,
                              hipStream_t stream) {
  const float* x   = (const float*)d_in[0];
  const int*   ei  = (const int*)d_in[1];
  const float* xo  = (const float*)d_in[3];
  const float* W1  = (const float*)d_in[4];  const float* b1  = (const float*)d_in[5];
  const float* W2  = (const float*)d_in[6];  const float* b2  = (const float*)d_in[7];
  const float* W3  = (const float*)d_in[8];  const float* b3  = (const float*)d_in[9];
  const float* Wg1 = (const float*)d_in[10]; const float* bg1 = (const float*)d_in[11];
  const float* Wg2 = (const float*)d_in[12]; const float* bg2 = (const float*)d_in[13];
  const float* k1  = (const float*)d_in[14]; const float* kb1 = (const float*)d_in[15];
  const float* k2  = (const float*)d_in[16]; const float* kb2 = (const float*)d_in[17];
  const float* k3  = (const float*)d_in[18]; const float* kb3 = (const float*)d_in[19];
  const float* Wxt = (const float*)d_in[20]; const float* bxt = (const float*)d_in[21];
  const float* Wf1 = (const float*)d_in[22]; const float* bf1 = (const float*)d_in[23];
  const float* Wf2 = (const float*)d_in[24]; const float* bf2 = (const float*)d_in[25];
  const float* Wo  = (const float*)d_in[26]; const float* bo  = (const float*)d_in[27];
  float* out = (float*)d_out;

  char* ws = (char*)d_ws;
  size_t off = 0;
  auto alloc = [&](size_t bytes) -> void* {
    void* p = ws + off;
    off += (bytes + 255) & ~(size_t)255;
    return p;
  };

  int*   indeg   = (int*)alloc((size_t)N_NODES * 4);
  float* dinv    = (float*)alloc((size_t)N_NODES * 4);
  int*   rowstart= (int*)alloc((size_t)(N_NODES + 1) * 4);
  int*   cursor  = (int*)alloc((size_t)N_NODES * 4);
  int*   bsums   = (int*)alloc(640 * 4);
  int*   boffs   = (int*)alloc(640 * 4);
  int*   csr     = (int*)alloc((size_t)N_EDGES * 4 + 256);
  bf16*  nb1     = (bf16*)alloc((size_t)N_NODES * 160 * 2);
  bf16*  nb2     = (bf16*)alloc((size_t)NB * 7744 * 2);
  bf16*  gb      = (bf16*)alloc((size_t)NB * 320 * 2);
  bf16*  g1b     = (bf16*)alloc((size_t)NB * 1024 * 2);
  bf16*  gtb     = (bf16*)alloc((size_t)NB * 256 * 2);
  float* f2      = (float*)alloc((size_t)NB * 128 * 4);
  bf16*  Wr2     = (bf16*)alloc((size_t)256 * 64 * 2);
  bf16*  Wr3     = (bf16*)alloc((size_t)512 * 128 * 2);
  bf16*  Btw1    = (bf16*)alloc((size_t)80 * 96 * 2);
  bf16*  Btw2    = (bf16*)alloc((size_t)160 * 96 * 2);
  bf16*  BtW3    = (bf16*)alloc((size_t)320 * 160 * 2);
  bf16*  Btg1    = (bf16*)alloc((size_t)1024 * 320 * 2);
  bf16*  Btg2    = (bf16*)alloc((size_t)128 * 1024 * 2);
  bf16*  Btxt    = (bf16*)alloc((size_t)128 * 2944 * 2);
  bf16*  Btf1    = (bf16*)alloc((size_t)1024 * 256 * 2);
  bf16*  Btf2    = (bf16*)alloc((size_t)128 * 1024 * 2);

  bf16* xb  = nb2;   // [N,80]
  bf16* h1  = nb1;   // [N,80]   (fused layer-1 out)
  bf16* h2  = nb2;   // [N,192]  (fused layer-2 out; xb dead)
  bf16* ag2 = nb1;   // [N,160]  (agg192 out; h1 dead)
  bf16* c2  = nb1;   // [B,78,64] (after gcn3 consumed ag2)
  bf16* c3  = nb2;   // [B,2944]  (h2 dead)
  bf16* f1b = g1b;

  // ---- weight prep + indeg zero (single launch) ----
  wprep_all_kernel<<<(WPREP_TOTAL + 255) / 256, 256, 0, stream>>>(
      k2, k3, W1, W2, W3, Wg1, Wg2, Wxt, Wf1, Wf2, Wr2, Wr3, Btw1, Btw2, BtW3,
      Btg1, Btg2, Btxt, Btf1, Btf2, indeg);

  // ---- CSR build + degree norm ----
  count_kernel<<<N_EDGES / 256, 256, 0, stream>>>(ei, indeg);
  scan1_kernel<<<640, 256, 0, stream>>>(indeg, rowstart, bsums, dinv);
  scan2_kernel<<<1, 640, 0, stream>>>(bsums, boffs, rowstart);
  scan3_kernel<<<640, 256, 0, stream>>>(rowstart, cursor, boffs);
  scatter_kernel<<<dim3(N_EDGES / 256, 4), 256, 0, stream>>>(ei, cursor, csr);

  // ---- GCN layers (fused gather+transform; dinv folded into stored features) ----
  cast_scale_kernel<<<(N_NODES * 80 + 255) / 256, 256, 0, stream>>>(x, dinv, xb);
  gcn_fused_kernel<5><<<N_NODES / 64, 256, 0, stream>>>(
      xb, dinv, rowstart, csr, Btw1, b1, h1, 78, 80);
  gcn_fused_kernel<12><<<N_NODES / 64, 256, 0, stream>>>(
      h1, dinv, rowstart, csr, Btw2, b2, h2, 156, 192);
  agg192_kernel<<<N_NODES / 4, 256, 0, stream>>>(h2, dinv, rowstart, csr, ag2);
  gcn3_segmax_mfma_kernel<<<NB / 4, 256, 0, stream>>>(ag2, BtW3, b3, gb);

  // ---- graph head (MFMA) ----
  gemm_mfma_kernel<4, bf16><<<dim3(NB / 64, 16), 256, 0, stream>>>(
      gb, Btg1, bg1, nullptr, g1b, NB, 1024, 1024, 10, 320, 320, 1024, 0, 1);
  gemm_mfma_kernel<4, bf16><<<dim3(NB / 64, 2), 256, 0, stream>>>(
      g1b, Btg2, bg2, nullptr, gtb, NB, 128, 128, 32, 1024, 1024, 256, 0, 0);

  // ---- conv tower (conv1 fused into conv2; runs after gcn3 so nb1 is free) ----
  conv12_kernel<<<NB / 2, 256, 0, stream>>>(xo, k1, kb1, Wr2, kb2, c2);
  convmfma_kernel<64, 78, 88, 5, 23, 4, 128>
      <<<dim3(NB / 4, 2), 256, 0, stream>>>(c2, Wr3, kb3, c3);
  gemm_mfma_kernel<4, bf16><<<dim3(NB / 64, 2), 256, 0, stream>>>(
      c3, Btxt, bxt, nullptr, gtb, NB, 128, 128, 92, 2944, 2944, 256, 128, 0);

  // ---- fused head (MFMA) ----
  gemm_mfma_kernel<4, bf16><<<dim3(NB / 64, 16), 256, 0, stream>>>(
      gtb, Btf1, bf1, nullptr, f1b, NB, 1024, 1024, 8, 256, 256, 1024, 0, 1);
  gemm_mfma_kernel<4, float><<<dim3(NB / 64, 2), 256, 0, stream>>>(
      f1b, Btf2, bf2, nullptr, f2, NB, 128, 128, 32, 1024, 1024, 128, 0, 1);
  final_kernel<<<NB * 64 / 256, 256, 0, stream>>>(f2, Wo, bo, out);
}

// Round 13
// 1152.929 us; speedup vs baseline: 1.0844x; 1.0844x over previous
//
#include <hip/hip_runtime.h>
#include <hip/hip_bf16.h>

#define N_NODES 163840
#define N_EDGES 2621440
#define NB      4096

typedef __hip_bfloat16 bf16;
typedef __attribute__((ext_vector_type(8))) short short8;
typedef __attribute__((ext_vector_type(4))) float floatx4;

__device__ inline float tofloat(float v) { return v; }
__device__ inline float tofloat(bf16 v) { return __bfloat162float(v); }
__device__ inline void storev(float* p, float v) { *p = v; }
__device__ inline void storev(bf16* p, float v) { *p = __float2bfloat16(v); }
__device__ inline float s2f(short s) {
  union { unsigned u; float f; } cv;
  cv.u = ((unsigned)(unsigned short)s) << 16;
  return cv.f;
}
__device__ inline short f2s(float f) {
  bf16 b = __float2bfloat16(f);
  return *(short*)&b;
}

// ======================= graph preprocessing =======================

__global__ __launch_bounds__(256) void zero_kernel(int* __restrict__ p) {
  p[blockIdx.x * 256 + threadIdx.x] = 0;
}

__global__ __launch_bounds__(256) void count_kernel(const int* __restrict__ ei,
                                                    int* __restrict__ indeg) {
  int e = blockIdx.x * 256 + threadIdx.x;
  if (e < N_EDGES) atomicAdd(&indeg[ei[N_EDGES + e]], 1);
}

// block-scan over indeg; also emits dinv = rsqrt(indeg+1)
__global__ __launch_bounds__(256) void scan1_kernel(const int* __restrict__ indeg,
                                                    int* __restrict__ rowstart,
                                                    int* __restrict__ bsums,
                                                    float* __restrict__ dinv) {
  __shared__ int s[256];
  int tid = threadIdx.x;
  int i = blockIdx.x * 256 + tid;
  int v = indeg[i];
  dinv[i] = rsqrtf((float)v + 1.0f);
  s[tid] = v;
  __syncthreads();
  for (int off = 1; off < 256; off <<= 1) {
    int x = (tid >= off) ? s[tid - off] : 0;
    __syncthreads();
    s[tid] += x;
    __syncthreads();
  }
  rowstart[i] = s[tid] - v;
  if (tid == 255) bsums[blockIdx.x] = s[255];
}

__global__ void scan2_kernel(const int* __restrict__ bsums, int* __restrict__ boffs,
                             int* __restrict__ rowstart) {
  if (threadIdx.x == 0 && blockIdx.x == 0) {
    int run = 0;
    for (int i = 0; i < 640; i++) { boffs[i] = run; run += bsums[i]; }
    rowstart[N_NODES] = run;
  }
}

__global__ __launch_bounds__(256) void scan3_kernel(int* __restrict__ rowstart,
                                                    int* __restrict__ cursor,
                                                    const int* __restrict__ boffs) {
  int i = blockIdx.x * 256 + threadIdx.x;
  int v = rowstart[i] + boffs[blockIdx.x];
  rowstart[i] = v;
  cursor[i] = v;
}

// Bucketed scatter: pass p = blockIdx.y commits only dst in [p*N/8,(p+1)*N/8).
// Blocks dispatch x-fastest, so passes run ~serially; each pass's 1.3 MB csr
// slice stays L2-resident, so each 64B line fills completely before writeback
// (fixes the 16x write amplification of the unbucketed scatter: WRITE 167MB->~20MB).
__global__ __launch_bounds__(256) void scatter_kernel(const int* __restrict__ ei,
                                                      int* __restrict__ cursor,
                                                      int* __restrict__ csr_src) {
  int e = blockIdx.x * 256 + threadIdx.x;
  int lo = blockIdx.y * (N_NODES / 8);
  int hi = lo + (N_NODES / 8);
  if (e < N_EDGES) {
    int d = ei[N_EDGES + e];
    if (d >= lo && d < hi) {
      int pos = atomicAdd(&cursor[d], 1);
      csr_src[pos] = ei[e];
    }
  }
}

// xb[n, 0:78] = x[n,:] * dinv[n]; cols 78..79 = 0  (padded [N,80] layout)
__global__ __launch_bounds__(256) void cast_scale_kernel(const float* __restrict__ x,
                                                         const float* __restrict__ dinv,
                                                         bf16* __restrict__ xb) {
  int i = blockIdx.x * 256 + threadIdx.x;
  if (i < N_NODES * 80) {
    int n = i / 80, f = i - n * 80;
    float v = (f < 78) ? x[n * 78 + f] * dinv[n] : 0.f;
    xb[i] = __float2bfloat16(v);
  }
}

// ======================= GCN aggregation (instruction-efficient gather) ============
// Inputs pre-scaled: hs[n] = h[n]*dinv[n].  out[n] = dn*(sum_src hs[src] + hs[n]).
// Rows gathered as per-lane 16B chunks, multiple rows per VMEM instruction.

// F=80 (160 B rows, 10 chunks): 6 lane-groups x 10 chunks (lanes 60-63 idle).
__global__ __launch_bounds__(256) void agg80_kernel(const bf16* __restrict__ hs,
                                                    const float* __restrict__ dinv,
                                                    const int* __restrict__ rowstart,
                                                    const int* __restrict__ csr,
                                                    bf16* __restrict__ out) {
  int node = blockIdx.x * 4 + (threadIdx.x >> 6);
  int lane = threadIdx.x & 63;
  int grp = lane / 10;          // 0..5 active, 6 idle
  int sub = lane - grp * 10;    // 0..9
  bool active = grp < 6;
  int st = rowstart[node], en = rowstart[node + 1];
  int cnt = en - st + 1;        // edges + self
  float dn = dinv[node];
  float acc[8];
#pragma unroll
  for (int j = 0; j < 8; j++) acc[j] = 0.f;
  for (int e = 0; e < cnt; e += 6) {
    int ri = e + grp;
    bool valid = active && (ri < cnt);
    int cidx = st + ri;
    cidx = (cidx < en) ? cidx : 0;
    int row = (ri < cnt - 1) ? csr[cidx] : node;
    const short* rp = (const short*)hs + (size_t)row * 80 + sub * 8;
    short8 d = *(const short8*)rp;
    float m = valid ? 1.f : 0.f;
#pragma unroll
    for (int j = 0; j < 8; j++) acc[j] += m * s2f(d[j]);
  }
  // reduce over the 6 groups: lanes sub, sub+10, ..., sub+50
  short ob[8];
#pragma unroll
  for (int j = 0; j < 8; j++) {
    float v = acc[j];
    float t = 0.f;
#pragma unroll
    for (int g = 0; g < 6; g++) t += __shfl(v, sub + 10 * g);
    ob[j] = f2s(t * dn);
  }
  if (grp == 0) {
    short8 pk;
#pragma unroll
    for (int j = 0; j < 8; j++) pk[j] = ob[j];
    *(short8*)((short*)out + (size_t)node * 80 + sub * 8) = pk;
  }
}

// F=192 gather (384 B rows = 3 aligned lines, 24 chunks), writes 160-wide.
// 8 lane-groups x 8 chunks; 3 chunk-loads (k=0,1,2) cover the row.
__global__ __launch_bounds__(256) void agg192_kernel(const bf16* __restrict__ hs,
                                                     const float* __restrict__ dinv,
                                                     const int* __restrict__ rowstart,
                                                     const int* __restrict__ csr,
                                                     bf16* __restrict__ out) {
  int node = blockIdx.x * 4 + (threadIdx.x >> 6);
  int lane = threadIdx.x & 63;
  int grp = lane >> 3;          // 0..7
  int sub = lane & 7;           // 0..7
  int st = rowstart[node], en = rowstart[node + 1];
  int cnt = en - st + 1;        // edges + self
  float dn = dinv[node];
  float acc[3][8];
#pragma unroll
  for (int k = 0; k < 3; k++)
#pragma unroll
    for (int j = 0; j < 8; j++) acc[k][j] = 0.f;
  for (int e = 0; e < cnt; e += 8) {
    int ri = e + grp;
    bool valid = ri < cnt;
    int cidx = st + ri;
    cidx = (cidx < en) ? cidx : 0;
    int row = (ri < cnt - 1) ? csr[cidx] : node;
    const short* rp = (const short*)hs + (size_t)row * 192 + sub * 8;
    float m = valid ? 1.f : 0.f;
#pragma unroll
    for (int k = 0; k < 3; k++) {
      short8 d = *(const short8*)(rp + k * 64);
#pragma unroll
      for (int j = 0; j < 8; j++) acc[k][j] += m * s2f(d[j]);
    }
  }
  // butterfly-reduce over the 8 groups (xor 8,16,32)
#pragma unroll
  for (int k = 0; k < 3; k++) {
    short8 pk;
#pragma unroll
    for (int j = 0; j < 8; j++) {
      float v = acc[k][j];
      v += __shfl_xor(v, 8);
      v += __shfl_xor(v, 16);
      v += __shfl_xor(v, 32);
      pk[j] = f2s(v * dn);
    }
    if (grp == 0 && (k < 2 || sub < 4))
      *(short8*)((short*)out + (size_t)node * 160 + k * 64 + sub * 8) = pk;
  }
}

// ======================= MFMA GEMM (direct-register, no LDS) =======================
template <int NT, typename TC>
__global__ __launch_bounds__(256) void gemm_mfma_kernel(
    const bf16* __restrict__ A, const bf16* __restrict__ Bt,
    const float* __restrict__ bias, const float* __restrict__ rowScale,
    TC* __restrict__ C, int M, int Nc, int ncstore, int Ksteps, int lda,
    int kpad, int ldc, int coff, int doRelu) {
  int tid = threadIdx.x;
  int w = tid >> 6, lane = tid & 63;
  int quad = lane >> 4, l16 = lane & 15;
  int r0 = blockIdx.x * 64 + w * 16;
  int c0 = blockIdx.y * (NT * 16);
  floatx4 acc[NT];
#pragma unroll
  for (int t = 0; t < NT; t++) acc[t] = (floatx4){0.f, 0.f, 0.f, 0.f};
  const short* Ap = (const short*)A + (size_t)(r0 + l16) * lda + quad * 8;
  const short* Bp = (const short*)Bt + (size_t)(c0 + l16) * kpad + quad * 8;
  for (int s = 0; s < Ksteps; s++) {
    short8 a = *(const short8*)(Ap + s * 32);
#pragma unroll
    for (int t = 0; t < NT; t++) {
      short8 b = *(const short8*)(Bp + (size_t)t * 16 * kpad + s * 32);
      acc[t] = __builtin_amdgcn_mfma_f32_16x16x32_bf16(a, b, acc[t], 0, 0, 0);
    }
  }
#pragma unroll
  for (int t = 0; t < NT; t++) {
    int c = c0 + t * 16 + l16;
    if (c >= ncstore) continue;
    bool valid = c < Nc;
    float bb = (bias && valid) ? bias[c] : 0.f;
#pragma unroll
    for (int r = 0; r < 4; r++) {
      int row = r0 + quad * 4 + r;
      float v = valid ? acc[t][r] + bb : 0.f;
      if (doRelu) v = fmaxf(v, 0.f);
      if (rowScale) v *= rowScale[row];
      storev(&C[(size_t)row * ldc + coff + c], v);
    }
  }
}

// ================== merged weight prep (one launch for all weights) ==================
__device__ inline void wtrans_one(const float* __restrict__ W, bf16* __restrict__ Bt,
                                  int K, int N, int Kpad, int idx) {
  int n = idx / Kpad, k = idx - n * Kpad;
  float v = (k < K && n < N) ? W[(size_t)k * N + n] : 0.f;
  Bt[idx] = __float2bfloat16(v);
}
template <int CI, int NCO>
__device__ inline void wprep_one(const float* __restrict__ kw, bf16* __restrict__ Wr,
                                 int idx) {
  int co = idx % NCO, k = idx / NCO;
  int dl = k / CI, ci = k % CI;
  Wr[idx] = __float2bfloat16(kw[(co * CI + ci) * 8 + dl]);
}
__global__ __launch_bounds__(256) void wprep_all_kernel(
    const float* k2, const float* k3, const float* W1, const float* W2,
    const float* W3, const float* Wg1, const float* Wg2, const float* Wxt,
    const float* Wf1, const float* Wf2, bf16* Wr2, bf16* Wr3, bf16* Btw1,
    bf16* Btw2, bf16* BtW3, bf16* Btg1, bf16* Btg2, bf16* Btxt, bf16* Btf1,
    bf16* Btf2) {
  int idx = blockIdx.x * 256 + threadIdx.x;
  if (idx < 16384) { wprep_one<32, 64>(k2, Wr2, idx); return; }
  idx -= 16384;
  if (idx < 65536) { wprep_one<64, 128>(k3, Wr3, idx); return; }
  idx -= 65536;
  if (idx < 7680) { wtrans_one(W1, Btw1, 78, 78, 96, idx); return; }
  idx -= 7680;
  if (idx < 15360) { wtrans_one(W2, Btw2, 78, 156, 96, idx); return; }
  idx -= 15360;
  if (idx < 51200) { wtrans_one(W3, BtW3, 156, 312, 160, idx); return; }
  idx -= 51200;
  if (idx < 327680) { wtrans_one(Wg1, Btg1, 312, 1024, 320, idx); return; }
  idx -= 327680;
  if (idx < 131072) { wtrans_one(Wg2, Btg2, 1024, 128, 1024, idx); return; }
  idx -= 131072;
  if (idx < 376832) {  // Wxt permuted transpose
    int o = idx / 2944, k = idx - o * 2944;
    int l = k >> 7, co = k & 127;
    Btxt[idx] = __float2bfloat16(Wxt[((size_t)(co * 23 + l)) * 128 + o]);
    return;
  }
  idx -= 376832;
  if (idx < 262144) { wtrans_one(Wf1, Btf1, 256, 1024, 256, idx); return; }
  idx -= 262144;
  if (idx < 131072) { wtrans_one(Wf2, Btf2, 1024, 128, 1024, idx); return; }
}
#define WPREP_TOTAL (16384 + 65536 + 7680 + 15360 + 51200 + 327680 + 131072 + 376832 + 262144 + 131072)

// ======= fused layer-3 GCN transform + bias + relu + segment-max (MFMA) =============
__global__ __launch_bounds__(256) void gcn3_segmax_mfma_kernel(
    const bf16* __restrict__ agg2, const bf16* __restrict__ BtW3,
    const float* __restrict__ b3, bf16* __restrict__ g) {
  __shared__ __align__(16) bf16 a_lds[160 * 168];
  int tid = threadIdx.x;
  int w = tid >> 6, lane = tid & 63;
  int quad = lane >> 4, l16 = lane & 15;
  int g0 = blockIdx.x * 4;

  short8 bfrag[5][5];
  const short* Bp = (const short*)BtW3 + (size_t)(w * 80 + l16) * 160 + quad * 8;
#pragma unroll
  for (int nt = 0; nt < 5; nt++)
#pragma unroll
    for (int ks = 0; ks < 5; ks++)
      bfrag[nt][ks] = *(const short8*)(Bp + (size_t)nt * 16 * 160 + ks * 32);

  const bf16* src = agg2 + (size_t)g0 * 40 * 160;
  for (int i = tid; i < 160 * 160 / 8; i += 256) {
    int flat = i * 8;
    int row = flat / 160, k = flat - row * 160;
    *(short8*)&a_lds[row * 168 + k] = *(const short8*)&src[flat];
  }
  __syncthreads();

  float gmax[5][4];
#pragma unroll
  for (int nt = 0; nt < 5; nt++)
#pragma unroll
    for (int gi = 0; gi < 4; gi++) gmax[nt][gi] = -3.0e38f;

#pragma unroll
  for (int mt = 0; mt < 10; mt++) {
    floatx4 acc[5];
#pragma unroll
    for (int nt = 0; nt < 5; nt++) acc[nt] = (floatx4){0.f, 0.f, 0.f, 0.f};
#pragma unroll
    for (int ks = 0; ks < 5; ks++) {
      short8 a = *(const short8*)&a_lds[(16 * mt + l16) * 168 + ks * 32 + quad * 8];
#pragma unroll
      for (int nt = 0; nt < 5; nt++)
        acc[nt] = __builtin_amdgcn_mfma_f32_16x16x32_bf16(a, bfrag[nt][ks], acc[nt], 0, 0, 0);
    }
    int gl = (16 * mt + quad * 4) / 40;
#pragma unroll
    for (int nt = 0; nt < 5; nt++) {
      float m4 = fmaxf(fmaxf(acc[nt][0], acc[nt][1]), fmaxf(acc[nt][2], acc[nt][3]));
#pragma unroll
      for (int gi = 0; gi < 4; gi++)
        if (gl == gi) gmax[nt][gi] = fmaxf(gmax[nt][gi], m4);
    }
  }

#pragma unroll
  for (int nt = 0; nt < 5; nt++) {
#pragma unroll
    for (int gi = 0; gi < 4; gi++) {
      float v = gmax[nt][gi];
      v = fmaxf(v, __shfl_xor(v, 16));
      v = fmaxf(v, __shfl_xor(v, 32));
      gmax[nt][gi] = v;
    }
    int c = w * 80 + nt * 16 + l16;
    float bb = (c < 312) ? b3[c] : 0.f;
    float val = fmaxf(gmax[nt][quad] + bb, 0.f);
    g[(size_t)(g0 + quad) * 320 + c] = __float2bfloat16(val);
  }
}

// ======================= conv1: [B,735] f32 -> [B,242,32] bf16 (pos-major) =========
__global__ __launch_bounds__(256) void conv1_kernel(const float* __restrict__ xo,
                                                    const float* __restrict__ k1,
                                                    const float* __restrict__ kb1,
                                                    bf16* __restrict__ out) {
  __shared__ float xin[735];
  int b = blockIdx.x, tid = threadIdx.x;
  for (int i = tid; i < 735; i += 256) xin[i] = xo[b * 735 + i];
  int co = tid & 31;
  float wreg[8];
#pragma unroll
  for (int k = 0; k < 8; k++) wreg[k] = k1[co * 8 + k];
  float bs = kb1[co];
  __syncthreads();
  for (int idx = tid; idx < 242 * 32; idx += 256) {
    int l = idx >> 5;
    int base = l * 3;
    float a0 = bs, a1 = bs, a2 = bs;
#pragma unroll
    for (int k = 0; k < 8; k++) {
      float wv = wreg[k];
      a0 += wv * xin[base + k];
      a1 += wv * xin[base + 1 + k];
      a2 += wv * xin[base + 2 + k];
    }
    out[(size_t)b * (242 * 32) + idx] =
        __float2bfloat16(fmaxf(0.f, fmaxf(a0, fmaxf(a1, a2))));
  }
}

// ======================= MFMA implicit-GEMM conv + bias + relu + pool3 ==============
template <int CI, int LIN, int LPAD, int MT, int LOUT, int G, int NCO>
__global__ __launch_bounds__(256) void convmfma_kernel(const bf16* __restrict__ in,
                                                       const bf16* __restrict__ Wr,
                                                       const float* __restrict__ kb,
                                                       bf16* __restrict__ outp) {
  constexpr int KSTEPS = 8 * CI / 32;
  constexpr int CIP = CI + 8;
  __shared__ __align__(16) bf16 lds_in[G * LPAD * CIP];
  __shared__ bf16 stg[4][MT * 16][16];
  int tid = threadIdx.x;
  int w = tid >> 6, lane = tid & 63;
  int quad = lane >> 4, l16 = lane & 15;
  int bg = blockIdx.x;
  int co0 = blockIdx.y * 64 + w * 16;

  short8 bfrag[KSTEPS];
#pragma unroll
  for (int s = 0; s < KSTEPS; s++) {
#pragma unroll
    for (int j = 0; j < 8; j++) {
      int k = s * 32 + quad * 8 + j;
      bfrag[s][j] = ((const short*)Wr)[k * NCO + co0 + l16];
    }
  }

  const bf16* gin = in + (size_t)bg * G * LIN * CI;
  constexpr int NELEM = G * LIN * CI;
  for (int i = tid; i < NELEM / 8; i += 256) {
    int flat = i * 8;
    int g = flat / (LIN * CI);
    int rem = flat - g * (LIN * CI);
    int row = rem / CI, ci = rem - row * CI;
    *(short8*)&lds_in[(g * LPAD + row) * CIP + ci] = *(const short8*)&gin[flat];
  }
  constexpr int PADE = G * (LPAD - LIN) * CIP;
  for (int i = tid; i < PADE / 8; i += 256) {
    int flat = i * 8;
    int g = flat / ((LPAD - LIN) * CIP);
    int rem = flat - g * ((LPAD - LIN) * CIP);
    short8 z = {0, 0, 0, 0, 0, 0, 0, 0};
    *(short8*)&lds_in[(g * LPAD + LIN) * CIP + rem] = z;
  }
  __syncthreads();

  for (int g = 0; g < G; g++) {
    const bf16* base = &lds_in[g * LPAD * CIP];
#pragma unroll
    for (int mt = 0; mt < MT; mt++) {
      floatx4 acc = {0.f, 0.f, 0.f, 0.f};
      int m = mt * 16 + l16;
#pragma unroll
      for (int s = 0; s < KSTEPS; s++) {
        int kg0 = s * 32 + quad * 8;
        int dl = kg0 / CI;
        int ci0 = kg0 % CI;
        short8 a = *(const short8*)&base[(m + dl) * CIP + ci0];
        acc = __builtin_amdgcn_mfma_f32_16x16x32_bf16(a, bfrag[s], acc, 0, 0, 0);
      }
#pragma unroll
      for (int r = 0; r < 4; r++)
        stg[w][mt * 16 + quad * 4 + r][l16] = __float2bfloat16(acc[r]);
    }
    __syncthreads();
    float bias = kb[co0 + l16];
    for (int it = lane; it < LOUT * 16; it += 64) {
      int l = it >> 4;
      float v0 = __bfloat162float(stg[w][3 * l][l16]);
      float v1 = __bfloat162float(stg[w][3 * l + 1][l16]);
      float v2 = __bfloat162float(stg[w][3 * l + 2][l16]);
      float v = fmaxf(fmaxf(v0, v1), v2) + bias;
      outp[((size_t)(bg * G + g) * LOUT + l) * NCO + co0 + l16] =
          __float2bfloat16(fmaxf(v, 0.f));
    }
    __syncthreads();
  }
}

// ======================= final head =======================
__global__ __launch_bounds__(256) void final_kernel(const float* __restrict__ f2,
                                                    const float* __restrict__ Wo,
                                                    const float* __restrict__ bo,
                                                    float* __restrict__ out) {
  int wid = (blockIdx.x * blockDim.x + threadIdx.x) >> 6;
  int lane = threadIdx.x & 63;
  if (wid >= NB) return;
  float s = f2[wid * 128 + lane] * Wo[lane] + f2[wid * 128 + 64 + lane] * Wo[64 + lane];
  for (int o = 32; o > 0; o >>= 1) s += __shfl_down(s, o);
  if (lane == 0) out[wid] = s + bo[0];
}

// ======================= launch =======================
extern "C" void kernel_launch(void* const* d_in, const int* in_sizes, int n_in,
                              void* d_out, int out_size, void* d_ws, size_t ws_size,
                              hipStream_t stream) {
  const float* x   = (const float*)d_in[0];
  const int*   ei  = (const int*)d_in[1];
  const float* xo  = (const float*)d_in[3];
  const float* W1  = (const float*)d_in[4];  const float* b1  = (const float*)d_in[5];
  const float* W2  = (const float*)d_in[6];  const float* b2  = (const float*)d_in[7];
  const float* W3  = (const float*)d_in[8];  const float* b3  = (const float*)d_in[9];
  const float* Wg1 = (const float*)d_in[10]; const float* bg1 = (const float*)d_in[11];
  const float* Wg2 = (const float*)d_in[12]; const float* bg2 = (const float*)d_in[13];
  const float* k1  = (const float*)d_in[14]; const float* kb1 = (const float*)d_in[15];
  const float* k2  = (const float*)d_in[16]; const float* kb2 = (const float*)d_in[17];
  const float* k3  = (const float*)d_in[18]; const float* kb3 = (const float*)d_in[19];
  const float* Wxt = (const float*)d_in[20]; const float* bxt = (const float*)d_in[21];
  const float* Wf1 = (const float*)d_in[22]; const float* bf1 = (const float*)d_in[23];
  const float* Wf2 = (const float*)d_in[24]; const float* bf2 = (const float*)d_in[25];
  const float* Wo  = (const float*)d_in[26]; const float* bo  = (const float*)d_in[27];
  float* out = (float*)d_out;

  char* ws = (char*)d_ws;
  size_t off = 0;
  auto alloc = [&](size_t bytes) -> void* {
    void* p = ws + off;
    off += (bytes + 255) & ~(size_t)255;
    return p;
  };

  int*   indeg   = (int*)alloc((size_t)N_NODES * 4);
  float* dinv    = (float*)alloc((size_t)N_NODES * 4);
  int*   rowstart= (int*)alloc((size_t)(N_NODES + 1) * 4);
  int*   cursor  = (int*)alloc((size_t)N_NODES * 4);
  int*   bsums   = (int*)alloc(640 * 4);
  int*   boffs   = (int*)alloc(640 * 4);
  int*   csr     = (int*)alloc((size_t)N_EDGES * 4 + 256);
  bf16*  nb1     = (bf16*)alloc((size_t)N_NODES * 160 * 2);
  bf16*  nb2     = (bf16*)alloc((size_t)NB * 7744 * 2);
  bf16*  gb      = (bf16*)alloc((size_t)NB * 320 * 2);
  bf16*  g1b     = (bf16*)alloc((size_t)NB * 1024 * 2);
  bf16*  gtb     = (bf16*)alloc((size_t)NB * 256 * 2);
  float* f2      = (float*)alloc((size_t)NB * 128 * 4);
  bf16*  Wr2     = (bf16*)alloc((size_t)256 * 64 * 2);
  bf16*  Wr3     = (bf16*)alloc((size_t)512 * 128 * 2);
  bf16*  Btw1    = (bf16*)alloc((size_t)80 * 96 * 2);
  bf16*  Btw2    = (bf16*)alloc((size_t)160 * 96 * 2);
  bf16*  BtW3    = (bf16*)alloc((size_t)320 * 160 * 2);
  bf16*  Btg1    = (bf16*)alloc((size_t)1024 * 320 * 2);
  bf16*  Btg2    = (bf16*)alloc((size_t)128 * 1024 * 2);
  bf16*  Btxt    = (bf16*)alloc((size_t)128 * 2944 * 2);
  bf16*  Btf1    = (bf16*)alloc((size_t)1024 * 256 * 2);
  bf16*  Btf2    = (bf16*)alloc((size_t)128 * 1024 * 2);

  bf16* xb  = nb2;   // [N,80]
  bf16* h   = nb2;   // h1 [N,80], h2 [N,192] (3 aligned 128B lines per row)
  bf16* ag  = nb1;   // agg buffers [N,80] / [N,160]
  bf16* c1  = nb2;   // [B,242,32]
  bf16* c2  = nb1;   // [B,78,64]
  bf16* c3  = nb2;   // [B,23,128] flat [B,2944]
  bf16* f1b = g1b;

  // ---- weight prep (single launch) ----
  wprep_all_kernel<<<(WPREP_TOTAL + 255) / 256, 256, 0, stream>>>(
      k2, k3, W1, W2, W3, Wg1, Wg2, Wxt, Wf1, Wf2, Wr2, Wr3, Btw1, Btw2, BtW3,
      Btg1, Btg2, Btxt, Btf1, Btf2);

  // ---- CSR build + degree norm ----
  zero_kernel<<<N_NODES / 256, 256, 0, stream>>>(indeg);
  count_kernel<<<N_EDGES / 256, 256, 0, stream>>>(ei, indeg);
  scan1_kernel<<<640, 256, 0, stream>>>(indeg, rowstart, bsums, dinv);
  scan2_kernel<<<1, 64, 0, stream>>>(bsums, boffs, rowstart);
  scan3_kernel<<<640, 256, 0, stream>>>(rowstart, cursor, boffs);
  scatter_kernel<<<dim3(N_EDGES / 256, 8), 256, 0, stream>>>(ei, cursor, csr);

  // ---- GCN layers (aggregate-first; dinv folded into stored features) ----
  cast_scale_kernel<<<(N_NODES * 80 + 255) / 256, 256, 0, stream>>>(x, dinv, xb);
  agg80_kernel<<<N_NODES / 4, 256, 0, stream>>>(xb, dinv, rowstart, csr, ag);
  gemm_mfma_kernel<5, bf16><<<dim3(N_NODES / 64, 1), 256, 0, stream>>>(
      ag, Btw1, b1, dinv, h, N_NODES, 78, 80, 3, 80, 96, 80, 0, 1);
  agg80_kernel<<<N_NODES / 4, 256, 0, stream>>>(h, dinv, rowstart, csr, ag);
  gemm_mfma_kernel<6, bf16><<<dim3(N_NODES / 64, 2), 256, 0, stream>>>(
      ag, Btw2, b2, dinv, h, N_NODES, 156, 192, 3, 80, 96, 192, 0, 1);
  agg192_kernel<<<N_NODES / 4, 256, 0, stream>>>(h, dinv, rowstart, csr, ag);
  gcn3_segmax_mfma_kernel<<<NB / 4, 256, 0, stream>>>(ag, BtW3, b3, gb);

  // ---- graph head (MFMA) ----
  gemm_mfma_kernel<4, bf16><<<dim3(NB / 64, 16), 256, 0, stream>>>(
      gb, Btg1, bg1, nullptr, g1b, NB, 1024, 1024, 10, 320, 320, 1024, 0, 1);
  gemm_mfma_kernel<4, bf16><<<dim3(NB / 64, 2), 256, 0, stream>>>(
      g1b, Btg2, bg2, nullptr, gtb, NB, 128, 128, 32, 1024, 1024, 256, 0, 0);

  // ---- conv tower (pos-major, MFMA) ----
  conv1_kernel<<<NB, 256, 0, stream>>>(xo, k1, kb1, c1);
  convmfma_kernel<32, 242, 248, 15, 78, 2, 64>
      <<<dim3(NB / 2, 1), 256, 0, stream>>>(c1, Wr2, kb2, c2);
  convmfma_kernel<64, 78, 88, 5, 23, 4, 128>
      <<<dim3(NB / 4, 2), 256, 0, stream>>>(c2, Wr3, kb3, c3);
  gemm_mfma_kernel<4, bf16><<<dim3(NB / 64, 2), 256, 0, stream>>>(
      c3, Btxt, bxt, nullptr, gtb, NB, 128, 128, 92, 2944, 2944, 256, 128, 0);

  // ---- fused head (MFMA) ----
  gemm_mfma_kernel<4, bf16><<<dim3(NB / 64, 16), 256, 0, stream>>>(
      gtb, Btf1, bf1, nullptr, f1b, NB, 1024, 1024, 8, 256, 256, 1024, 0, 1);
  gemm_mfma_kernel<4, float><<<dim3(NB / 64, 2), 256, 0, stream>>>(
      f1b, Btf2, bf2, nullptr, f2, NB, 128, 128, 32, 1024, 1024, 128, 0, 1);
  final_kernel<<<NB * 64 / 256, 256, 0, stream>>>(f2, Wo, bo, out);
}